// Round 1
// baseline (577.840 us; speedup 1.0000x reference)
//
#include <hip/hip_runtime.h>

#define L_IN   2048
#define C_IN   512
#define L_OUT  2045
#define TL     16
#define XT_PAD 21   // LDS row stride for xt[c][*] (19 used, padded to 21)

// Twiddle factor offsets (g, diag, row, col):
//  f1: g=512 d=1  r=4 c=4   @ 0      (8192)
//  f2: g=64  d=4  r=8 c=8   @ 8192   (16384)
//  f3: g=8   d=32 r=4 c=8   @ 24576  (8192)
//  f4: g=1   d=64 r=8 c=16  @ 32768  (8192)
// t[g,r,c,d] = flat[((g*diag + d)*row + r)*col + c]

__global__ __launch_bounds__(256)
void debut_fused_kernel(const float* __restrict__ x,
                        const float* __restrict__ tw,
                        const float* __restrict__ bias,
                        float* __restrict__ out)
{
    __shared__ float xt[C_IN * XT_PAD];  // 43008 B
    __shared__ float bufA[2048];         // 8192 B
    __shared__ float bufB[2048];         // 8192 B

    const int tile = blockIdx.x;   // 0..127
    const int b    = blockIdx.y;   // 0..15
    const int l0   = tile * TL;
    const int tid  = threadIdx.x;

    // ---- stage x[b, c, l0 .. l0+18] -> xt[c][0..18] ----
    const float* xb = x + (size_t)b * C_IN * L_IN;
    for (int idx = tid; idx < C_IN * 19; idx += 256) {
        int c  = idx / 19;
        int ll = idx - c * 19;
        int l  = l0 + ll;
        xt[c * XT_PAD + ll] = (l < L_IN) ? xb[c * L_IN + l] : 0.0f;
    }
    __syncthreads();

    const float* t1 = tw;
    const float* t2 = tw + 8192;
    const float* t3 = tw + 24576;
    const float* t4 = tw + 32768;

    for (int rr = 0; rr < TL; ++rr) {
        const int l = l0 + rr;
        if (l >= L_OUT) break;   // uniform across block

        // ---- factor 1 (2048 outputs), fused im2col gather ----
        // o = gb*4 + r ; input j = gb*4 + c' -> k = gb>>7, c = (gb&127)*4 + c'
        #pragma unroll
        for (int i = 0; i < 8; ++i) {
            int o  = tid + 256 * i;
            int gb = o >> 2;
            int k  = gb >> 7;
            int cb = (gb & 127) << 2;
            const float4 t = *reinterpret_cast<const float4*>(t1 + o * 4);
            const float* xp = &xt[cb * XT_PAD + rr + k];
            bufA[o] = t.x * xp[0] + t.y * xp[XT_PAD] + t.z * xp[2 * XT_PAD] + t.w * xp[3 * XT_PAD];
        }
        __syncthreads();

        // ---- factor 2 (2048 outputs): o = gb*32 + r*4 + d ----
        #pragma unroll
        for (int i = 0; i < 8; ++i) {
            int o  = tid + 256 * i;
            int gb = o >> 5;
            int r  = (o >> 2) & 7;
            int d  = o & 3;
            const float* tp = t2 + (((gb << 2) + d) * 8 + r) * 8;
            const float* ip = &bufA[(gb << 5) + d];
            float acc = 0.0f;
            #pragma unroll
            for (int c = 0; c < 8; ++c) acc += tp[c] * ip[c << 2];
            bufB[o] = acc;
        }
        __syncthreads();

        // ---- factor 3 (1024 outputs): o = gb*128 + r*32 + d ----
        #pragma unroll
        for (int i = 0; i < 4; ++i) {
            int o  = tid + 256 * i;
            int gb = o >> 7;
            int r  = (o >> 5) & 3;
            int d  = o & 31;
            const float* tp = t3 + (((gb << 5) + d) * 4 + r) * 8;
            const float* ip = &bufB[(gb << 8) + d];
            float acc = 0.0f;
            #pragma unroll
            for (int c = 0; c < 8; ++c) acc += tp[c] * ip[c << 5];
            bufA[o] = acc;   // bufA free: factor-2 reads completed before its barrier
        }
        __syncthreads();

        // ---- factor 4 (512 outputs): o = r*64 + d ----
        #pragma unroll
        for (int i = 0; i < 2; ++i) {
            int o = tid + 256 * i;
            int r = o >> 6;
            int d = o & 63;
            const float* tp = t4 + ((d << 3) + r) * 16;
            float acc = 0.0f;
            #pragma unroll
            for (int c = 0; c < 16; ++c) acc += tp[c] * bufA[(c << 6) + d];
            out[((size_t)(b * 512 + o)) * L_OUT + l] = acc + bias[o];
        }
        __syncthreads();  // protect bufA before next row's factor 1
    }
}

extern "C" void kernel_launch(void* const* d_in, const int* in_sizes, int n_in,
                              void* d_out, int out_size, void* d_ws, size_t ws_size,
                              hipStream_t stream) {
    const float* x    = (const float*)d_in[0];
    const float* tw   = (const float*)d_in[1];
    const float* bias = (const float*)d_in[2];
    float* out = (float*)d_out;

    dim3 grid(128, 16);   // 128 l-tiles of 16 (covers 2045 with guard) x 16 batches
    debut_fused_kernel<<<grid, dim3(256), 0, stream>>>(x, tw, bias, out);
}

// Round 2
// 236.689 us; speedup vs baseline: 2.4414x; 2.4414x over previous
//
#include <hip/hip_runtime.h>

#define L_IN   2048
#define C_IN   512
#define L_OUT  2045
#define XT_PAD 21

typedef short short8 __attribute__((ext_vector_type(8)));
typedef float float4v __attribute__((ext_vector_type(4)));

__device__ __forceinline__ unsigned short bf16r(float f) {
    unsigned u = __float_as_uint(f);
    unsigned r = (u + 0x7FFFu + ((u >> 16) & 1u)) >> 16;
    return (unsigned short)r;
}

// swizzle: XOR bits 4,5 with bits 7,8 (row bits 1,2 of 64B rows). Involution.
__device__ __forceinline__ int SWZ(int u) { return u ^ (((u >> 7) & 3) << 4); }

#define GLB_AS1(p) ((const __attribute__((address_space(1))) unsigned int*)(p))
#define LDS_AS3(p) ((__attribute__((address_space(3))) unsigned int*)(p))

// ---------------- kernel 1: build dense composite W (512 x 2048) in bf16 ----------------
// W[o][j] = sum_{q=0,1} t4 * t3 * t2 * t1  (exactly 2 paths per entry)
__global__ __launch_bounds__(256)
void build_w(const float* __restrict__ tw, unsigned short* __restrict__ W) {
    int idx = blockIdx.x * 256 + threadIdx.x;   // o*2048 + j, 1M total
    int o = idx >> 11, j = idx & 2047;
    float s = 0.f;
    #pragma unroll
    for (int q = 0; q < 2; ++q) {
        float t1 = tw[ ((j >> 2) << 4) + ((o & 3) << 2) + (j & 3) ];
        float t2 = tw[ 8192 + ((((j >> 5) * 4 + (o & 3)) * 8 + ((o >> 2) & 7)) * 8) + ((j >> 2) & 7) ];
        float t3 = tw[ 24576 + ((((j >> 8) * 32 + (o & 31)) * 4 + (2 * q + ((o >> 5) & 1))) * 8) + ((j >> 5) & 7) ];
        float t4 = tw[ 32768 + (((o & 63) * 8 + (o >> 6)) * 16) + ((j >> 8) * 2 + q) ];
        s += t4 * t3 * t2 * t1;
    }
    W[idx] = bf16r(s);
}

// ---------------- kernel 2: im2col -> bf16 R[b][l(2048 pad)][2048] ----------------
// R[b*2048 + l][koff*512 + c] = x[b][c][l + koff]
__global__ __launch_bounds__(256)
void im2col_bf16(const float* __restrict__ x, unsigned short* __restrict__ R) {
    const int lt   = blockIdx.x;      // 0..15
    const int b    = blockIdx.y;      // 0..15
    const int cblk = blockIdx.z;      // 0..7  (64 c each)
    const int l0   = lt * 128;
    const int t    = threadIdx.x;
    const int cc   = t & 7;           // 8 c-chunks of 8
    const int lq   = t >> 3;          // 0..31
    const int c0   = cblk * 64 + cc * 8;

    const float* xb = x + (size_t)b * C_IN * L_IN;
    unsigned short* Rb = R + ((size_t)b * 2048) * 2048;

    for (int ls = 0; ls < 4; ++ls) {
        int l = lq * 4 + ls;          // 0..127
        #pragma unroll
        for (int koff = 0; koff < 4; ++koff) {
            int lx = l0 + l + koff; if (lx > L_IN - 1) lx = L_IN - 1;
            unsigned short v[8];
            #pragma unroll
            for (int s = 0; s < 8; ++s)
                v[s] = bf16r(xb[(size_t)(c0 + s) * L_IN + lx]);
            *(uint4*)&Rb[(size_t)(l0 + l) * 2048 + koff * 512 + c0] = *(const uint4*)v;
        }
    }
}

// ---------------- kernel 3: GEMM  C[o][m] = W(512x2048) . R(m x 2048)^T + bias ----------------
// 128x128 tile, BK=32, 4 waves (2x2 of 64x64), global_load_lds staging, swizzled LDS.
__global__ __launch_bounds__(256)
void gemm_bf16(const unsigned short* __restrict__ W, const unsigned short* __restrict__ R,
               const float* __restrict__ bias, float* __restrict__ out) {
    __shared__ short Wt[4096];   // [128 o][32 k] swizzled, 8 KB
    __shared__ short Rt[4096];   // [128 m][32 k] swizzled, 8 KB

    const int gx = blockIdx.x;
    const int ot = gx & 3, lt = (gx >> 2) & 15, b = gx >> 6;
    const int o0 = ot * 128;
    const int t = threadIdx.x;
    const int lane = t & 63;
    const int wv = t >> 6;                 // wave 0..3
    const int wo = (wv >> 1) * 64;         // wave o-offset
    const int wm = (wv & 1) * 64;          // wave m-offset
    const int lr = lane & 15, lh = lane >> 4;

    const unsigned short* Wb = W + (size_t)o0 * 2048;
    const unsigned short* Rb = R + ((size_t)b * 2048 + (size_t)lt * 128) * 2048;

    float4v acc[4][4] = {};

    for (int kb = 0; kb < 64; ++kb) {
        __syncthreads();   // previous iter's ds_reads retired before overwrite
        #pragma unroll
        for (int q = 0; q < 2; ++q) {
            int i = q * 256 + t;                 // chunk 0..511
            int sbyte = i << 4;                  // linear LDS dest byte
            int u = SWZ(sbyte);                  // logical (unswizzled) byte
            int r  = u >> 6;                     // row 0..127
            int kc = (u >> 4) & 3;               // 16B chunk in row
            size_t goff = (size_t)r * 2048 + (size_t)kb * 32 + kc * 8;  // elements
            int ldsbase = (q * 256 + wv * 64) << 4;   // wave-uniform base
            __builtin_amdgcn_global_load_lds(GLB_AS1(Wb + goff), LDS_AS3((char*)Wt + ldsbase), 16, 0, 0);
            __builtin_amdgcn_global_load_lds(GLB_AS1(Rb + goff), LDS_AS3((char*)Rt + ldsbase), 16, 0, 0);
        }
        __syncthreads();   // drains vmcnt before use

        short8 af[4], bf[4];
        #pragma unroll
        for (int f = 0; f < 4; ++f) {
            int ua = (wo + f * 16 + lr) * 64 + lh * 16;
            af[f] = *(const short8*)((const char*)Wt + SWZ(ua));
            int ub = (wm + f * 16 + lr) * 64 + lh * 16;
            bf[f] = *(const short8*)((const char*)Rt + SWZ(ub));
        }
        #pragma unroll
        for (int i = 0; i < 4; ++i)
            #pragma unroll
            for (int jf = 0; jf < 4; ++jf)
                acc[i][jf] = __builtin_amdgcn_mfma_f32_16x16x32_bf16(af[i], bf[jf], acc[i][jf], 0, 0, 0);
    }

    // epilogue: C row = o (A), col = m (B); col = lane&15 -> consecutive l = coalesced
    const int lbase = lt * 128 + wm;
    #pragma unroll
    for (int i = 0; i < 4; ++i) {
        int obase = o0 + wo + i * 16 + lh * 4;
        #pragma unroll
        for (int jf = 0; jf < 4; ++jf) {
            int lpos = lbase + jf * 16 + lr;
            if (lpos < L_OUT) {
                #pragma unroll
                for (int r = 0; r < 4; ++r) {
                    int oo = obase + r;
                    out[((size_t)(b * 512 + oo)) * L_OUT + lpos] = acc[i][jf][r] + bias[oo];
                }
            }
        }
    }
}

// ---------------- fallback (round-1 kernel, used if ws too small) ----------------
__global__ __launch_bounds__(256)
void debut_fused_kernel(const float* __restrict__ x,
                        const float* __restrict__ tw,
                        const float* __restrict__ bias,
                        float* __restrict__ out)
{
    __shared__ float xt[C_IN * XT_PAD];
    __shared__ float bufA[2048];
    __shared__ float bufB[2048];

    const int tile = blockIdx.x;
    const int b    = blockIdx.y;
    const int l0   = tile * 16;
    const int tid  = threadIdx.x;

    const float* xb = x + (size_t)b * C_IN * L_IN;
    for (int idx = tid; idx < C_IN * 19; idx += 256) {
        int c  = idx / 19;
        int ll = idx - c * 19;
        int l  = l0 + ll;
        xt[c * XT_PAD + ll] = (l < L_IN) ? xb[c * L_IN + l] : 0.0f;
    }
    __syncthreads();

    const float* t1 = tw;
    const float* t2 = tw + 8192;
    const float* t3 = tw + 24576;
    const float* t4 = tw + 32768;

    for (int rr = 0; rr < 16; ++rr) {
        const int l = l0 + rr;
        if (l >= L_OUT) break;
        #pragma unroll
        for (int i = 0; i < 8; ++i) {
            int o  = tid + 256 * i;
            int gb = o >> 2;
            int k  = gb >> 7;
            int cb = (gb & 127) << 2;
            const float4 tq = *reinterpret_cast<const float4*>(t1 + o * 4);
            const float* xp = &xt[cb * XT_PAD + rr + k];
            bufA[o] = tq.x * xp[0] + tq.y * xp[XT_PAD] + tq.z * xp[2 * XT_PAD] + tq.w * xp[3 * XT_PAD];
        }
        __syncthreads();
        #pragma unroll
        for (int i = 0; i < 8; ++i) {
            int o  = tid + 256 * i;
            int gb = o >> 5;
            int r  = (o >> 2) & 7;
            int d  = o & 3;
            const float* tp = t2 + (((gb << 2) + d) * 8 + r) * 8;
            const float* ip = &bufA[(gb << 5) + d];
            float acc = 0.0f;
            #pragma unroll
            for (int c = 0; c < 8; ++c) acc += tp[c] * ip[c << 2];
            bufB[o] = acc;
        }
        __syncthreads();
        #pragma unroll
        for (int i = 0; i < 4; ++i) {
            int o  = tid + 256 * i;
            int gb = o >> 7;
            int r  = (o >> 5) & 3;
            int d  = o & 31;
            const float* tp = t3 + (((gb << 5) + d) * 4 + r) * 8;
            const float* ip = &bufB[(gb << 8) + d];
            float acc = 0.0f;
            #pragma unroll
            for (int c = 0; c < 8; ++c) acc += tp[c] * ip[c << 5];
            bufA[o] = acc;
        }
        __syncthreads();
        #pragma unroll
        for (int i = 0; i < 2; ++i) {
            int o = tid + 256 * i;
            int r = o >> 6;
            int d = o & 63;
            const float* tp = t4 + ((d << 3) + r) * 16;
            float acc = 0.0f;
            #pragma unroll
            for (int c = 0; c < 16; ++c) acc += tp[c] * bufA[(c << 6) + d];
            out[((size_t)(b * 512 + o)) * L_OUT + l] = acc + bias[o];
        }
        __syncthreads();
    }
}

extern "C" void kernel_launch(void* const* d_in, const int* in_sizes, int n_in,
                              void* d_out, int out_size, void* d_ws, size_t ws_size,
                              hipStream_t stream) {
    const float* x    = (const float*)d_in[0];
    const float* tw   = (const float*)d_in[1];
    const float* bias = (const float*)d_in[2];
    float* out = (float*)d_out;

    const size_t W_BYTES = (size_t)512 * 2048 * 2;              // 2 MB
    const size_t R_BYTES = (size_t)16 * 2048 * 2048 * 2;        // 128 MB
    if (ws_size < W_BYTES + R_BYTES) {
        dim3 grid(128, 16);
        debut_fused_kernel<<<grid, dim3(256), 0, stream>>>(x, tw, bias, out);
        return;
    }

    unsigned short* Wd = (unsigned short*)d_ws;
    unsigned short* Rd = (unsigned short*)((char*)d_ws + W_BYTES);

    build_w<<<dim3(4096), dim3(256), 0, stream>>>(tw, Wd);
    im2col_bf16<<<dim3(16, 16, 8), dim3(256), 0, stream>>>(x, Rd);
    gemm_bf16<<<dim3(1024), dim3(256), 0, stream>>>(Wd, Rd, bias, out);
}

// Round 3
// 62.720 us; speedup vs baseline: 9.2130x; 3.7737x over previous
//
#include <hip/hip_runtime.h>

#define L_IN   2048
#define C_IN   512
#define L_OUT  2045
#define XT_PAD 21
#define O2S    2056   // out2 LDS row stride (elements): 16B-aligned, bank offset 4/m

typedef short short8 __attribute__((ext_vector_type(8)));
typedef float float4v __attribute__((ext_vector_type(4)));

__device__ __forceinline__ unsigned short bf16r(float f) {
    unsigned u = __float_as_uint(f);
    unsigned r = (u + 0x7FFFu + ((u >> 16) & 1u)) >> 16;
    return (unsigned short)r;
}

// ---------------- kernel 1: build W21/W43 in MFMA A-fragment layout ----------------
// W21[g][a][e] = t2[g,d2,r2,c2]*t1[g*8+c2, d2, c1]   (a=r2*4+d2, e=c2*4+c1)  64 blocks 32x32
// W43[s][u][w] = sum_lo t4[d4,r4,2p+lo]*t3[p,s,2lo+hi,c3]  (u=r4*2+hi, d4=hi*32+s, w=p*8+c3) 32 blocks 16x64
// frag layout: lane holds 8 consecutive k at row=lane&15, kchunk=(lane>>4)*8
__global__ __launch_bounds__(256)
void build_wf(const float* __restrict__ tw, unsigned short* __restrict__ W21f,
              unsigned short* __restrict__ W43f) {
    int id = blockIdx.x * 256 + threadIdx.x;
    if (id < 65536) {
        int p = id & 7, lane = (id >> 3) & 63, oh = (id >> 9) & 1, g = id >> 10;
        int a = oh * 16 + (lane & 15);
        int e = ((lane >> 4) & 3) * 8 + p;
        int r2 = a >> 2, d2 = a & 3, c2 = e >> 2, c1 = e & 3;
        float v = tw[8192 + ((g * 4 + d2) * 8 + r2) * 8 + c2]
                * tw[(g * 8 + c2) * 16 + d2 * 4 + c1];
        W21f[id] = bf16r(v);
    } else if (id < 98304) {
        int id2 = id - 65536;
        int p = id2 & 7, lane = (id2 >> 3) & 63, kh = (id2 >> 9) & 1, s = id2 >> 10;
        int u = lane & 15;
        int w = kh * 32 + ((lane >> 4) & 3) * 8 + p;
        int r4 = u >> 1, hi = u & 1, d4 = hi * 32 + s, p2 = w >> 3, c3 = w & 7;
        float v = 0.f;
        #pragma unroll
        for (int lo = 0; lo < 2; ++lo)
            v += tw[32768 + (d4 * 8 + r4) * 16 + (2 * p2 + lo)]
               * tw[24576 + ((p2 * 32 + s) * 4 + (2 * lo + hi)) * 8 + c3];
        W43f[id2] = bf16r(v);
    }
}

// ---------------- kernel 2: transpose x (b,c,l) f32 -> xT (b,l,c) bf16 ----------------
__global__ __launch_bounds__(256)
void transpose_x(const float* __restrict__ x, unsigned short* __restrict__ xT) {
    __shared__ unsigned short tile[64 * 66];
    const int lt = blockIdx.x, ct = blockIdx.y, b = blockIdx.z;
    const int l0 = lt * 64, c0 = ct * 64;
    const int t = threadIdx.x;
    const float* xb = x + ((size_t)b * C_IN + c0) * L_IN + l0;

    #pragma unroll
    for (int pass = 0; pass < 4; ++pass) {
        int c  = pass * 16 + (t >> 4);
        int lc = (t & 15) * 4;
        float4 v = *reinterpret_cast<const float4*>(xb + (size_t)c * L_IN + lc);
        unsigned u0 = (unsigned)bf16r(v.x) | ((unsigned)bf16r(v.y) << 16);
        unsigned u1 = (unsigned)bf16r(v.z) | ((unsigned)bf16r(v.w) << 16);
        *(unsigned*)&tile[c * 66 + lc]     = u0;
        *(unsigned*)&tile[c * 66 + lc + 2] = u1;
    }
    __syncthreads();

    const int l = t >> 2, cc = (t & 3) * 16;
    unsigned short v[16];
    #pragma unroll
    for (int j = 0; j < 16; ++j) v[j] = tile[(cc + j) * 66 + l];
    unsigned short* dst = xT + ((size_t)b * L_IN + l0 + l) * C_IN + c0 + cc;
    *(uint4*)dst       = *(const uint4*)&v[0];
    *(uint4*)(dst + 8) = *(const uint4*)&v[8];
}

// ---------------- kernel 3: two-stage block-sparse MFMA ----------------
// Stage A: out2[m][j2] for j2=g*32+a: per g (64): [32a x 32e] @ v-rows (im2col from xT)
//   stored s-major: out2L[m][a*64 + (g ^ key(a))], key(a)=((a>>2)&3)<<4
// Stage B: out[o4] for o4=s+32u: per s (32): [16u x 64w] @ out2 rows
__global__ __launch_bounds__(512)
void debut_mfma(const unsigned short* __restrict__ W21f,
                const unsigned short* __restrict__ W43f,
                const unsigned short* __restrict__ xT,
                const float* __restrict__ bias, float* __restrict__ out) {
    extern __shared__ __align__(16) unsigned short out2[];   // [32][O2S]

    const int blk = blockIdx.x;          // 1024 = 16 b * 64 ltiles
    const int lt = blk & 63, b = blk >> 6;
    const int l0 = lt * 32;
    const int t = threadIdx.x;
    const int lane = t & 63, wv = t >> 6;        // 8 waves
    const int lr = lane & 15, lh = lane >> 4;

    const unsigned short* xTb = xT + (size_t)b * L_IN * C_IN;

    // ---- stage A: wave wv handles g = wv*8 .. wv*8+7 ----
    #pragma unroll
    for (int gi = 0; gi < 8; ++gi) {
        const int g = wv * 8 + gi;
        const int koff = g >> 4;
        const int c0 = (g & 15) * 32;

        short8 bfrag[2];
        #pragma unroll
        for (int mh = 0; mh < 2; ++mh) {
            int m = mh * 16 + lr;
            int lx = l0 + m + koff; if (lx > L_IN - 1) lx = L_IN - 1;
            bfrag[mh] = *(const short8*)(xTb + (size_t)lx * C_IN + c0 + lh * 8);
        }
        #pragma unroll
        for (int oh = 0; oh < 2; ++oh) {
            short8 afrag = *(const short8*)(W21f + ((size_t)(g * 2 + oh) * 64 + lane) * 8);
            #pragma unroll
            for (int mh = 0; mh < 2; ++mh) {
                float4v acc = {};
                acc = __builtin_amdgcn_mfma_f32_16x16x32_bf16(afrag, bfrag[mh], acc, 0, 0, 0);
                int m = mh * 16 + lr;
                #pragma unroll
                for (int i = 0; i < 4; ++i) {
                    int a = oh * 16 + lh * 4 + i;
                    int key = ((a >> 2) & 3) << 4;
                    out2[m * O2S + a * 64 + (g ^ key)] = bf16r(acc[i]);
                }
            }
        }
    }
    __syncthreads();

    // ---- stage B: wave wv handles s = wv*4 .. wv*4+3 ----
    #pragma unroll
    for (int si = 0; si < 4; ++si) {
        const int s = wv * 4 + si;
        const int key = ((s >> 2) & 3) << 4;
        short8 a0 = *(const short8*)(W43f + ((size_t)(s * 2 + 0) * 64 + lane) * 8);
        short8 a1 = *(const short8*)(W43f + ((size_t)(s * 2 + 1) * 64 + lane) * 8);
        #pragma unroll
        for (int mh = 0; mh < 2; ++mh) {
            int m = mh * 16 + lr;
            short8 b0 = *(const short8*)(&out2[m * O2S + s * 64 + (( 0 + lh * 8) ^ key)]);
            short8 b1 = *(const short8*)(&out2[m * O2S + s * 64 + ((32 + lh * 8) ^ key)]);
            float4v acc = {};
            acc = __builtin_amdgcn_mfma_f32_16x16x32_bf16(a0, b0, acc, 0, 0, 0);
            acc = __builtin_amdgcn_mfma_f32_16x16x32_bf16(a1, b1, acc, 0, 0, 0);
            int lpos = l0 + m;
            if (lpos < L_OUT) {
                #pragma unroll
                for (int i = 0; i < 4; ++i) {
                    int o4 = s + 32 * (lh * 4 + i);
                    out[((size_t)(b * 512 + o4)) * L_OUT + lpos] = acc[i] + bias[o4];
                }
            }
        }
    }
}

// ---------------- fallback (round-1 kernel, used if ws too small) ----------------
__global__ __launch_bounds__(256)
void debut_fused_kernel(const float* __restrict__ x,
                        const float* __restrict__ tw,
                        const float* __restrict__ bias,
                        float* __restrict__ out)
{
    __shared__ float xt[C_IN * XT_PAD];
    __shared__ float bufA[2048];
    __shared__ float bufB[2048];
    const int tile = blockIdx.x, b = blockIdx.y;
    const int l0 = tile * 16;
    const int tid = threadIdx.x;
    const float* xb = x + (size_t)b * C_IN * L_IN;
    for (int idx = tid; idx < C_IN * 19; idx += 256) {
        int c = idx / 19, ll = idx - c * 19, l = l0 + ll;
        xt[c * XT_PAD + ll] = (l < L_IN) ? xb[c * L_IN + l] : 0.0f;
    }
    __syncthreads();
    const float* t1 = tw; const float* t2 = tw + 8192;
    const float* t3 = tw + 24576; const float* t4 = tw + 32768;
    for (int rr = 0; rr < 16; ++rr) {
        const int l = l0 + rr;
        if (l >= L_OUT) break;
        #pragma unroll
        for (int i = 0; i < 8; ++i) {
            int o = tid + 256 * i, gb = o >> 2, k = gb >> 7, cb = (gb & 127) << 2;
            const float4 tq = *reinterpret_cast<const float4*>(t1 + o * 4);
            const float* xp = &xt[cb * XT_PAD + rr + k];
            bufA[o] = tq.x * xp[0] + tq.y * xp[XT_PAD] + tq.z * xp[2 * XT_PAD] + tq.w * xp[3 * XT_PAD];
        }
        __syncthreads();
        #pragma unroll
        for (int i = 0; i < 8; ++i) {
            int o = tid + 256 * i, gb = o >> 5, r = (o >> 2) & 7, d = o & 3;
            const float* tp = t2 + (((gb << 2) + d) * 8 + r) * 8;
            const float* ip = &bufA[(gb << 5) + d];
            float acc = 0.0f;
            #pragma unroll
            for (int c = 0; c < 8; ++c) acc += tp[c] * ip[c << 2];
            bufB[o] = acc;
        }
        __syncthreads();
        #pragma unroll
        for (int i = 0; i < 4; ++i) {
            int o = tid + 256 * i, gb = o >> 7, r = (o >> 5) & 3, d = o & 31;
            const float* tp = t3 + (((gb << 5) + d) * 4 + r) * 8;
            const float* ip = &bufB[(gb << 8) + d];
            float acc = 0.0f;
            #pragma unroll
            for (int c = 0; c < 8; ++c) acc += tp[c] * ip[c << 5];
            bufA[o] = acc;
        }
        __syncthreads();
        #pragma unroll
        for (int i = 0; i < 2; ++i) {
            int o = tid + 256 * i, r = o >> 6, d = o & 63;
            const float* tp = t4 + ((d << 3) + r) * 16;
            float acc = 0.0f;
            #pragma unroll
            for (int c = 0; c < 16; ++c) acc += tp[c] * bufA[(c << 6) + d];
            out[((size_t)(b * 512 + o)) * L_OUT + l] = acc + bias[o];
        }
        __syncthreads();
    }
}

extern "C" void kernel_launch(void* const* d_in, const int* in_sizes, int n_in,
                              void* d_out, int out_size, void* d_ws, size_t ws_size,
                              hipStream_t stream) {
    const float* x    = (const float*)d_in[0];
    const float* tw   = (const float*)d_in[1];
    const float* bias = (const float*)d_in[2];
    float* out = (float*)d_out;

    const size_t W21_B = 65536 * 2;                       // 128 KB
    const size_t W43_B = 32768 * 2;                       // 64 KB
    const size_t XT_B  = (size_t)16 * L_IN * C_IN * 2;    // 32 MB
    const int    LDS_B = 32 * O2S * 2;                    // 131584

    if (ws_size < W21_B + W43_B + XT_B) {
        dim3 grid(128, 16);
        debut_fused_kernel<<<grid, dim3(256), 0, stream>>>(x, tw, bias, out);
        return;
    }

    unsigned short* W21f = (unsigned short*)d_ws;
    unsigned short* W43f = (unsigned short*)((char*)d_ws + W21_B);
    unsigned short* xTd  = (unsigned short*)((char*)d_ws + W21_B + W43_B);

    (void)hipFuncSetAttribute((const void*)debut_mfma,
                              hipFuncAttributeMaxDynamicSharedMemorySize, LDS_B);

    build_wf<<<dim3(384), dim3(256), 0, stream>>>(tw, W21f, W43f);
    transpose_x<<<dim3(32, 8, 16), dim3(256), 0, stream>>>(x, xTd);
    debut_mfma<<<dim3(1024), dim3(512), (size_t)LDS_B, stream>>>(W21f, W43f, xTd, bias, out);
}